// Round 1
// baseline (240.377 us; speedup 1.0000x reference)
//
#include <hip/hip_runtime.h>
#include <math.h>

#define NSTATE 64
#define LEN    4096
#define NH     256
#define NB     16

// Symmetrized, base-4-digit-reversed frequency kernel: g_ksym[h][p] = Ksym[h][rev4(p)]
__device__ float2 g_ksym[NH * LEN];

__device__ __forceinline__ int rev4_12(int p) {
  // reverse 6 base-4 digits of a 12-bit index: bit-reverse then swap adjacent bit pairs
  int x = (int)(__brev((unsigned)p) >> 20);
  return ((x & 0x555) << 1) | ((x >> 1) & 0x555);
}

__global__ __launch_bounds__(1024) void s4_kernel_freq(
    const float* __restrict__ Lre, const float* __restrict__ Lim,
    const float* __restrict__ Pre, const float* __restrict__ Pim,
    const float* __restrict__ Bre, const float* __restrict__ Bim,
    const float* __restrict__ Cre, const float* __restrict__ Cim,
    const float* __restrict__ log_step)
{
  __shared__ float lamr[NSTATE], lami[NSTATE];
  __shared__ float v0r[NSTATE], v0i[NSTATE], v1r[NSTATE], v1i[NSTATE];
  __shared__ float v2r[NSTATE], v2i[NSTATE], v3r[NSTATE];
  __shared__ float2 kf[LEN];

  const int h = blockIdx.x;
  const int tid = threadIdx.x;

  if (tid < NSTATE) {
    int idx = h * NSTATE + tid;
    float lr = Lre[idx], li = Lim[idx];
    float pr = Pre[idx], pi = Pim[idx];
    float br = Bre[idx], bi = Bim[idx];
    float cr = Cre[idx], ci = Cim[idx];
    lamr[tid] = lr; lami[tid] = li;
    // conj(C)*B, conj(C)*P, conj(P)*B, conj(P)*P (last is real)
    v0r[tid] = cr * br + ci * bi;  v0i[tid] = cr * bi - ci * br;
    v1r[tid] = cr * pr + ci * pi;  v1i[tid] = cr * pi - ci * pr;
    v2r[tid] = pr * br + pi * bi;  v2i[tid] = pr * bi - pi * br;
    v3r[tid] = pr * pr + pi * pi;
  }
  __syncthreads();

  const float step = expf(log_step[h]);
  const float ts = 2.0f / step;
  const float NEG2PI = -6.2831853071795864769f;  // rounds to fp32 like reference

  for (int l = tid; l < LEN; l += 1024) {
    float frac = (float)l * (1.0f / (float)LEN);  // exact in fp32
    float ang = NEG2PI * frac;                    // matches jnp fp32 rounding
    float so, co;
    sincosf(ang, &so, &co);
    // den = 1 + Omega
    float dr = 1.0f + co, di = so;
    float inv = 1.0f / (dr * dr + di * di);
    float c_re = 2.0f * dr * inv, c_im = -2.0f * di * inv;   // c = 2/(1+Om)
    float nr = 1.0f - co, ni = -so;                           // 1 - Omega
    float g_re = ts * ((nr * dr + ni * di) * inv);            // g = (2/step)(1-Om)/(1+Om)
    float g_im = ts * ((ni * dr - nr * di) * inv);

    float k00r = 0.f, k00i = 0.f, k01r = 0.f, k01i = 0.f;
    float k10r = 0.f, k10i = 0.f, k11r = 0.f, k11i = 0.f;
#pragma unroll 8
    for (int n = 0; n < NSTATE; ++n) {
      float rd = g_re - lamr[n];
      float id = g_im - lami[n];
      float idn = 1.0f / (rd * rd + id * id);
      float ir = rd * idn, ii = -id * idn;   // 1/(g - lambda_n)
      k00r += v0r[n] * ir - v0i[n] * ii;  k00i += v0r[n] * ii + v0i[n] * ir;
      k01r += v1r[n] * ir - v1i[n] * ii;  k01i += v1r[n] * ii + v1i[n] * ir;
      k10r += v2r[n] * ir - v2i[n] * ii;  k10i += v2r[n] * ii + v2i[n] * ir;
      k11r += v3r[n] * ir;                k11i += v3r[n] * ii;
    }
    // Kf = c * (k00 - k01*k10/(1+k11))
    float rr = 1.0f + k11r, ri = k11i;
    float rinv = 1.0f / (rr * rr + ri * ri);
    float pr_ = k01r * k10r - k01i * k10i;
    float pi_ = k01r * k10i + k01i * k10r;
    float wr = (pr_ * rr + pi_ * ri) * rinv;
    float wi = (pi_ * rr - pr_ * ri) * rinv;
    float sr = k00r - wr, si = k00i - wi;
    kf[l] = make_float2(c_re * sr - c_im * si, c_re * si + c_im * sr);
  }
  __syncthreads();

  // Hermitian-symmetrize (so ifft(U*Ksym) is exactly real for real u),
  // store in base-4 digit-reversed order for the DIF/DIT convolution.
  float2* out = &g_ksym[(size_t)h * LEN];
  for (int p = tid; p < LEN; p += 1024) {
    int kk = rev4_12(p);
    float2 a = kf[kk];
    float2 b = kf[(LEN - kk) & (LEN - 1)];
    out[p] = make_float2(0.5f * (a.x + b.x), 0.5f * (a.y - b.y));
  }
}

__global__ __launch_bounds__(512) void s4_fftconv(const float* __restrict__ u,
                                                 float* __restrict__ y)
{
  __shared__ float2 X[LEN];
  __shared__ float2 TW[LEN / 4];   // TW[j] = exp(-2*pi*i*j/LEN), j in [0,1024)

  const int tid = threadIdx.x;
  const int bid = blockIdx.x;
  const int h  = bid & (NH - 1);
  const int bp = bid >> 8;         // 0..7 -> batches (bp, bp+8)

  const float TWC = -6.2831853071795864769f / (float)LEN;
  for (int j = tid; j < LEN / 4; j += 512) {
    float s, c;
    sincosf((float)j * TWC, &s, &c);
    TW[j] = make_float2(c, s);
  }

  const float* u1 = u + ((size_t)bp * NH + h) * LEN;
  const float* u2 = u + ((size_t)(bp + 8) * NH + h) * LEN;
  // pack two real sequences into one complex sequence
  const float4* u14 = (const float4*)u1;
  const float4* u24 = (const float4*)u2;
  for (int l4 = tid; l4 < LEN / 4; l4 += 512) {
    float4 a = u14[l4];
    float4 b = u24[l4];
    int l = l4 * 4;
    X[l + 0] = make_float2(a.x, b.x);
    X[l + 1] = make_float2(a.y, b.y);
    X[l + 2] = make_float2(a.z, b.z);
    X[l + 3] = make_float2(a.w, b.w);
  }
  __syncthreads();

  // ---- forward radix-4 DIF (natural in -> base-4 digit-reversed out) ----
  for (int e = 6; e >= 1; --e) {
    const int q = 1 << (2 * e - 2);
    const int tsh = 12 - 2 * e;
    for (int t = tid; t < LEN / 4; t += 512) {
      int j = t & (q - 1);
      int i0 = ((t >> (2 * e - 2)) << (2 * e)) + j;
      float2 x0 = X[i0], x1 = X[i0 + q], x2 = X[i0 + 2 * q], x3 = X[i0 + 3 * q];
      float t0r = x0.x + x2.x, t0i = x0.y + x2.y;
      float t1r = x0.x - x2.x, t1i = x0.y - x2.y;
      float t2r = x1.x + x3.x, t2i = x1.y + x3.y;
      float t3r = x1.x - x3.x, t3i = x1.y - x3.y;
      X[i0] = make_float2(t0r + t2r, t0i + t2i);
      float a1r = t1r + t3i, a1i = t1i - t3r;   // t1 - i*t3
      float a2r = t0r - t2r, a2i = t0i - t2i;
      float a3r = t1r - t3i, a3i = t1i + t3r;   // t1 + i*t3
      float2 w1 = TW[j << tsh];
      float w2r = w1.x * w1.x - w1.y * w1.y, w2i = 2.0f * w1.x * w1.y;
      float w3r = w2r * w1.x - w2i * w1.y,  w3i = w2r * w1.y + w2i * w1.x;
      X[i0 + q]     = make_float2(a1r * w1.x - a1i * w1.y, a1r * w1.y + a1i * w1.x);
      X[i0 + 2 * q] = make_float2(a2r * w2r - a2i * w2i,  a2r * w2i + a2i * w2r);
      X[i0 + 3 * q] = make_float2(a3r * w3r - a3i * w3i,  a3r * w3i + a3i * w3r);
    }
    __syncthreads();
  }

  // ---- pointwise multiply by symmetrized kernel (digit-reversed domain) ----
  const float2* kp = &g_ksym[(size_t)h * LEN];
  for (int l = tid; l < LEN; l += 512) {
    float2 k = kp[l];
    float2 x = X[l];
    X[l] = make_float2(x.x * k.x - x.y * k.y, x.x * k.y + x.y * k.x);
  }
  __syncthreads();

  // ---- inverse radix-4 DIT (digit-reversed in -> natural out), conj twiddles ----
  for (int e = 1; e <= 6; ++e) {
    const int q = 1 << (2 * e - 2);
    const int tsh = 12 - 2 * e;
    for (int t = tid; t < LEN / 4; t += 512) {
      int j = t & (q - 1);
      int i0 = ((t >> (2 * e - 2)) << (2 * e)) + j;
      float2 wt = TW[j << tsh];
      float w1r = wt.x, w1i = -wt.y;            // exp(+2*pi*i*j/m)
      float w2r = w1r * w1r - w1i * w1i, w2i = 2.0f * w1r * w1i;
      float w3r = w2r * w1r - w2i * w1i, w3i = w2r * w1i + w2i * w1r;
      float2 x0 = X[i0];
      float2 xa = X[i0 + q], xb = X[i0 + 2 * q], xc = X[i0 + 3 * q];
      float u1r = xa.x * w1r - xa.y * w1i, u1i = xa.x * w1i + xa.y * w1r;
      float u2r = xb.x * w2r - xb.y * w2i, u2i = xb.x * w2i + xb.y * w2r;
      float u3r = xc.x * w3r - xc.y * w3i, u3i = xc.x * w3i + xc.y * w3r;
      float t0r = x0.x + u2r, t0i = x0.y + u2i;
      float t1r = x0.x - u2r, t1i = x0.y - u2i;
      float t2r = u1r + u3r,  t2i = u1i + u3i;
      float t3r = u1r - u3r,  t3i = u1i - u3i;
      X[i0]         = make_float2(t0r + t2r, t0i + t2i);
      X[i0 + q]     = make_float2(t1r - t3i, t1i + t3r);   // t1 + i*t3
      X[i0 + 2 * q] = make_float2(t0r - t2r, t0i - t2i);
      X[i0 + 3 * q] = make_float2(t1r + t3i, t1i - t3r);   // t1 - i*t3
    }
    __syncthreads();
  }

  // unpack: y1 = Re, y2 = Im (both exactly real thanks to Ksym symmetrization)
  float* y1 = y + ((size_t)bp * NH + h) * LEN;
  float* y2 = y + ((size_t)(bp + 8) * NH + h) * LEN;
  const float sc = 1.0f / (float)LEN;
  float4* y14 = (float4*)y1;
  float4* y24 = (float4*)y2;
  for (int l4 = tid; l4 < LEN / 4; l4 += 512) {
    int l = l4 * 4;
    float2 a0 = X[l + 0], a1 = X[l + 1], a2 = X[l + 2], a3 = X[l + 3];
    y14[l4] = make_float4(a0.x * sc, a1.x * sc, a2.x * sc, a3.x * sc);
    y24[l4] = make_float4(a0.y * sc, a1.y * sc, a2.y * sc, a3.y * sc);
  }
}

extern "C" void kernel_launch(void* const* d_in, const int* in_sizes, int n_in,
                              void* d_out, int out_size, void* d_ws, size_t ws_size,
                              hipStream_t stream) {
  const float* u    = (const float*)d_in[0];
  const float* Lre  = (const float*)d_in[1];
  const float* Lim  = (const float*)d_in[2];
  const float* Pre  = (const float*)d_in[3];
  const float* Pim  = (const float*)d_in[4];
  const float* Bre  = (const float*)d_in[5];
  const float* Bim  = (const float*)d_in[6];
  const float* Cre  = (const float*)d_in[7];
  const float* Cim  = (const float*)d_in[8];
  const float* lstep = (const float*)d_in[9];
  float* y = (float*)d_out;

  s4_kernel_freq<<<NH, 1024, 0, stream>>>(Lre, Lim, Pre, Pim, Bre, Bim, Cre, Cim, lstep);
  s4_fftconv<<<NH * (NB / 2), 512, 0, stream>>>(u, y);
}

// Round 2
// 192.350 us; speedup vs baseline: 1.2497x; 1.2497x over previous
//
#include <hip/hip_runtime.h>
#include <math.h>

#define NSTATE 64
#define LEN    4096
#define NH     256
#define NB     16

// Ksym (Hermitian-symmetrized K) stored in base-8 digit-reversed order
__device__ float2 g_ksym[NH * LEN];
// per-(h,n) Cauchy params: A={lam_r,lam_i,v3r,pad} B={v0r,v0i,v1r,v1i} C={v2r,v2i}
__device__ float4 g_pA[NH * NSTATE];
__device__ float4 g_pB[NH * NSTATE];
__device__ float2 g_pC[NH * NSTATE];

__device__ __forceinline__ int rev8_12(int p) {
  // reverse four base-8 digits of a 12-bit index (involution)
  return ((p & 7) << 9) | (((p >> 3) & 7) << 6) | (((p >> 6) & 7) << 3) | (p >> 9);
}

// ---------------- complex helpers ----------------
__device__ __forceinline__ float2 cadd(float2 a, float2 b){ return make_float2(a.x+b.x, a.y+b.y); }
__device__ __forceinline__ float2 csub(float2 a, float2 b){ return make_float2(a.x-b.x, a.y-b.y); }
__device__ __forceinline__ float2 cmul(float2 a, float2 b){ return make_float2(a.x*b.x - a.y*b.y, a.x*b.y + a.y*b.x); }
__device__ __forceinline__ float2 mulnegi(float2 a){ return make_float2(a.y, -a.x); }   // a * (-i)
__device__ __forceinline__ float2 mulposi(float2 a){ return make_float2(-a.y, a.x); }   // a * (+i)

#define RSQ2 0.70710678118654752f

// y_m = sum_p x_p w8^{pm},  w8 = e^{-2*pi*i/8}
__device__ __forceinline__ void bfly8_fwd(float2 v[8]) {
  float2 a0 = cadd(v[0], v[4]), b0 = csub(v[0], v[4]);
  float2 a1 = cadd(v[1], v[5]), d1 = csub(v[1], v[5]);
  float2 a2 = cadd(v[2], v[6]), d2 = csub(v[2], v[6]);
  float2 a3 = cadd(v[3], v[7]), d3 = csub(v[3], v[7]);
  float2 b1 = make_float2(RSQ2 * (d1.x + d1.y), RSQ2 * (d1.y - d1.x));   // *(1-i)/s2
  float2 b2 = mulnegi(d2);
  float2 b3 = make_float2(RSQ2 * (d3.y - d3.x), -RSQ2 * (d3.x + d3.y));  // *-(1+i)/s2
  float2 u0 = cadd(a0, a2), u1 = csub(a0, a2), u2 = cadd(a1, a3), u3 = csub(a1, a3);
  v[0] = cadd(u0, u2);
  v[2] = cadd(u1, mulnegi(u3));
  v[4] = csub(u0, u2);
  v[6] = cadd(u1, mulposi(u3));
  float2 w0 = cadd(b0, b2), w1 = csub(b0, b2), w2 = cadd(b1, b3), w3 = csub(b1, b3);
  v[1] = cadd(w0, w2);
  v[3] = cadd(w1, mulnegi(w3));
  v[5] = csub(w0, w2);
  v[7] = cadd(w1, mulposi(w3));
}

// y_p = sum_m x_m w8c^{pm},  w8c = e^{+2*pi*i/8}
__device__ __forceinline__ void bfly8_inv(float2 v[8]) {
  float2 a0 = cadd(v[0], v[4]), b0 = csub(v[0], v[4]);
  float2 a1 = cadd(v[1], v[5]), d1 = csub(v[1], v[5]);
  float2 a2 = cadd(v[2], v[6]), d2 = csub(v[2], v[6]);
  float2 a3 = cadd(v[3], v[7]), d3 = csub(v[3], v[7]);
  float2 b1 = make_float2(RSQ2 * (d1.x - d1.y), RSQ2 * (d1.x + d1.y));   // *(1+i)/s2
  float2 b2 = mulposi(d2);
  float2 b3 = make_float2(-RSQ2 * (d3.x + d3.y), RSQ2 * (d3.x - d3.y));  // *(-1+i)/s2
  float2 u0 = cadd(a0, a2), u1 = csub(a0, a2), u2 = cadd(a1, a3), u3 = csub(a1, a3);
  v[0] = cadd(u0, u2);
  v[2] = cadd(u1, mulposi(u3));
  v[4] = csub(u0, u2);
  v[6] = cadd(u1, mulnegi(u3));
  float2 w0 = cadd(b0, b2), w1 = csub(b0, b2), w2 = cadd(b1, b3), w3 = csub(b1, b3);
  v[1] = cadd(w0, w2);
  v[3] = cadd(w1, mulposi(w3));
  v[5] = csub(w0, w2);
  v[7] = cadd(w1, mulnegi(w3));
}

// v[m] *= w^m for m=1..7 (w = (wr,wi)); powers via shallow product tree
__device__ __forceinline__ void twiddle7(float2 v[8], float wr, float wi) {
  float2 w1 = make_float2(wr, wi);
  float2 w2 = cmul(w1, w1);
  float2 w3 = cmul(w2, w1);
  float2 w4 = cmul(w2, w2);
  float2 w5 = cmul(w3, w2);
  float2 w6 = cmul(w3, w3);
  float2 w7 = cmul(w4, w3);
  v[1] = cmul(v[1], w1); v[2] = cmul(v[2], w2); v[3] = cmul(v[3], w3);
  v[4] = cmul(v[4], w4); v[5] = cmul(v[5], w5); v[6] = cmul(v[6], w6);
  v[7] = cmul(v[7], w7);
}

// ---------------- param precompute ----------------
__global__ __launch_bounds__(256) void s4_prep(
    const float* __restrict__ Lre, const float* __restrict__ Lim,
    const float* __restrict__ Pre, const float* __restrict__ Pim,
    const float* __restrict__ Bre, const float* __restrict__ Bim,
    const float* __restrict__ Cre, const float* __restrict__ Cim)
{
  int idx = blockIdx.x * 256 + threadIdx.x;
  if (idx >= NH * NSTATE) return;
  float lr = Lre[idx], li = Lim[idx];
  float pr = Pre[idx], pi = Pim[idx];
  float br = Bre[idx], bi = Bim[idx];
  float cr = Cre[idx], ci = Cim[idx];
  g_pA[idx] = make_float4(lr, li, pr * pr + pi * pi, 0.0f);
  g_pB[idx] = make_float4(cr * br + ci * bi, cr * bi - ci * br,
                          cr * pr + ci * pi, cr * pi - ci * pr);
  g_pC[idx] = make_float2(pr * br + pi * bi, pr * bi - pi * br);
}

// ---------------- frequency-domain S4 kernel ----------------
__global__ __launch_bounds__(1024) void s4_kernel_freq(const float* __restrict__ log_step)
{
  __shared__ float2 kf[LEN];   // XOR-swizzled layout: phys(i) = i ^ ((i>>6)&63)
  const int h = blockIdx.x, tid = threadIdx.x;
  const float step = expf(log_step[h]);
  const float ts = 2.0f / step;
  const float NEG2PI = -6.2831853071795864769f;

  float gr[4], gi[4];
#pragma unroll
  for (int j = 0; j < 4; ++j) {
    int l = tid + 1024 * j;
    float ang = NEG2PI * ((float)l * (1.0f / (float)LEN));
    float so, co; sincosf(ang, &so, &co);
    float dr = 1.0f + co, di = so;
    float inv = 1.0f / (dr * dr + di * di);
    float nr = 1.0f - co, ni = -so;
    gr[j] = ts * ((nr * dr + ni * di) * inv);
    gi[j] = ts * ((ni * dr - nr * di) * inv);
  }

  float k00r[4] = {0,0,0,0}, k00i[4] = {0,0,0,0};
  float k01r[4] = {0,0,0,0}, k01i[4] = {0,0,0,0};
  float k10r[4] = {0,0,0,0}, k10i[4] = {0,0,0,0};
  float k11r[4] = {0,0,0,0}, k11i[4] = {0,0,0,0};

  const float4* __restrict__ pa = g_pA + h * NSTATE;
  const float4* __restrict__ pb = g_pB + h * NSTATE;
  const float2* __restrict__ pc = g_pC + h * NSTATE;

#pragma unroll 4
  for (int n = 0; n < NSTATE; ++n) {
    float4 A  = pa[n];
    float4 Bv = pb[n];
    float2 Cv = pc[n];
#pragma unroll
    for (int j = 0; j < 4; ++j) {
      float rd = gr[j] - A.x, id = gi[j] - A.y;
      float idn = __builtin_amdgcn_rcpf(fmaf(rd, rd, id * id));
      float ir = rd * idn, ii = -id * idn;        // 1/(g - lambda_n)
      k00r[j] += Bv.x * ir - Bv.y * ii;  k00i[j] += Bv.x * ii + Bv.y * ir;
      k01r[j] += Bv.z * ir - Bv.w * ii;  k01i[j] += Bv.z * ii + Bv.w * ir;
      k10r[j] += Cv.x * ir - Cv.y * ii;  k10i[j] += Cv.x * ii + Cv.y * ir;
      k11r[j] += A.z * ir;               k11i[j] += A.z * ii;
    }
  }

#pragma unroll
  for (int j = 0; j < 4; ++j) {
    int l = tid + 1024 * j;
    float ang = NEG2PI * ((float)l * (1.0f / (float)LEN));
    float so, co; sincosf(ang, &so, &co);
    float dr = 1.0f + co, di = so;
    float inv = 1.0f / (dr * dr + di * di);
    float c_re = 2.0f * dr * inv, c_im = -2.0f * di * inv;
    float rr = 1.0f + k11r[j], ri = k11i[j];
    float rinv = 1.0f / (rr * rr + ri * ri);
    float pr_ = k01r[j] * k10r[j] - k01i[j] * k10i[j];
    float pi_ = k01r[j] * k10i[j] + k01i[j] * k10r[j];
    float wr = (pr_ * rr + pi_ * ri) * rinv;
    float wi = (pi_ * rr - pr_ * ri) * rinv;
    float sr = k00r[j] - wr, si = k00i[j] - wi;
    int ph = l ^ ((l >> 6) & 63);
    kf[ph] = make_float2(c_re * sr - c_im * si, c_re * si + c_im * sr);
  }
  __syncthreads();

  // symmetrize + rev8 reorder; swizzled reads keep the gather at 4-way
  float2* out = &g_ksym[(size_t)h * LEN];
  for (int p = tid; p < LEN; p += 1024) {
    int kk = rev8_12(p);
    int k2 = (LEN - kk) & (LEN - 1);
    float2 a = kf[kk ^ ((kk >> 6) & 63)];
    float2 b = kf[k2 ^ ((k2 >> 6) & 63)];
    out[p] = make_float2(0.5f * (a.x + b.x), 0.5f * (a.y - b.y));
  }
}

// ---------------- FFT convolution: register radix-8, 4096 = 8^4 ----------------
__global__ __launch_bounds__(512) void s4_fftconv(const float* __restrict__ u,
                                                 float* __restrict__ y)
{
  __shared__ float2 X[4608];   // max of: identity 4096, pitch-68 4352, pitch-9 4608

  const int t = threadIdx.x;
  const int bid = blockIdx.x;
  const int h  = bid & (NH - 1);
  const int bp = bid >> 8;       // packs batches (bp, bp+8)

  // twiddle bases (forward sign; inverse conjugates)
  float c1, s1, c2, s2, c3, s3;
  sincosf((float)t         * (-6.2831853071795864769f / 4096.0f), &s1, &c1);
  sincosf((float)(t & 63)  * (-6.2831853071795864769f /  512.0f), &s2, &c2);
  sincosf((float)(t & 7)   * (-6.2831853071795864769f /   64.0f), &s3, &c3);

  const float* u1 = u + ((size_t)bp * NH + h) * LEN;
  const float* u2 = u + ((size_t)(bp + 8) * NH + h) * LEN;

  float2 v[8];
  // ---- fwd stage 0 (M=4096, stride 512): load direct from global, coalesced
#pragma unroll
  for (int m = 0; m < 8; ++m)
    v[m] = make_float2(u1[t + 512 * m], u2[t + 512 * m]);
  bfly8_fwd(v);
  twiddle7(v, c1, s1);
#pragma unroll
  for (int m = 0; m < 8; ++m) X[t + 512 * m] = v[m];   // identity layout
  __syncthreads();

  // ---- fwd stage 1 (M=512, stride 64): contiguous reads
  {
    int B = t >> 6, j = t & 63, base = B * 512 + j;
#pragma unroll
    for (int m = 0; m < 8; ++m) v[m] = X[base + 64 * m];
  }
  __syncthreads();
  bfly8_fwd(v);
  twiddle7(v, c2, s2);
  {
    int B = t >> 6, j = t & 63;
#pragma unroll
    for (int m = 0; m < 8; ++m) X[68 * (8 * B + m) + j] = v[m];  // pitch-68, conflict-free
  }
  __syncthreads();

  // ---- fwd stage 2 (M=64, stride 8)
  {
    int b = t >> 3, j = t & 7;
#pragma unroll
    for (int m = 0; m < 8; ++m) v[m] = X[68 * b + j + 8 * m];    // 2-way, free
  }
  __syncthreads();
  bfly8_fwd(v);
  twiddle7(v, c3, s3);
  {
    int b = t >> 3, j = t & 7;
#pragma unroll
    for (int m = 0; m < 8; ++m) X[9 * (8 * b + m) + j] = v[m];   // pitch-9, 4-way
  }
  __syncthreads();

  // ---- fused middle: fwd stage 3 + pointwise K + inv stage A, all in registers
  {
    const float4* kp = (const float4*)(g_ksym + (size_t)h * LEN + 8 * t);
    float4 k0 = kp[0], k1 = kp[1], k2 = kp[2], k3 = kp[3];  // issue early, overlap LDS
#pragma unroll
    for (int m = 0; m < 8; ++m) v[m] = X[9 * t + m];        // row t: private to this thread
    bfly8_fwd(v);                                           // M=8, no twiddle
    v[0] = cmul(v[0], make_float2(k0.x, k0.y));
    v[1] = cmul(v[1], make_float2(k0.z, k0.w));
    v[2] = cmul(v[2], make_float2(k1.x, k1.y));
    v[3] = cmul(v[3], make_float2(k1.z, k1.w));
    v[4] = cmul(v[4], make_float2(k2.x, k2.y));
    v[5] = cmul(v[5], make_float2(k2.z, k2.w));
    v[6] = cmul(v[6], make_float2(k3.x, k3.y));
    v[7] = cmul(v[7], make_float2(k3.z, k3.w));
    bfly8_inv(v);                                           // inv M=8, no twiddle
#pragma unroll
    for (int p = 0; p < 8; ++p) X[9 * t + p] = v[p];        // same private row
  }
  __syncthreads();

  // ---- inv stage B (M=64, stride 8): twiddle inputs, then butterfly
  {
    int b = t >> 3, j = t & 7;
#pragma unroll
    for (int m = 0; m < 8; ++m) v[m] = X[9 * (8 * b + m) + j];
  }
  twiddle7(v, c3, -s3);
  bfly8_inv(v);
  __syncthreads();
  {
    int b = t >> 3, j = t & 7;
#pragma unroll
    for (int p = 0; p < 8; ++p) X[68 * b + j + 8 * p] = v[p];
  }
  __syncthreads();

  // ---- inv stage C (M=512, stride 64)
  {
    int B = t >> 6, j = t & 63;
#pragma unroll
    for (int m = 0; m < 8; ++m) v[m] = X[68 * (8 * B + m) + j];
  }
  twiddle7(v, c2, -s2);
  bfly8_inv(v);
  __syncthreads();
  {
    int B = t >> 6, j = t & 63, base = B * 512 + j;
#pragma unroll
    for (int p = 0; p < 8; ++p) X[base + 64 * p] = v[p];     // identity layout
  }
  __syncthreads();

  // ---- inv stage D (M=4096, stride 512): results land in natural order
#pragma unroll
  for (int m = 0; m < 8; ++m) v[m] = X[t + 512 * m];
  twiddle7(v, c1, -s1);
  bfly8_inv(v);

  float* y1 = y + ((size_t)bp * NH + h) * LEN;
  float* y2 = y + ((size_t)(bp + 8) * NH + h) * LEN;
  const float sc = 1.0f / (float)LEN;
#pragma unroll
  for (int p = 0; p < 8; ++p) {
    y1[t + 512 * p] = v[p].x * sc;   // batch bp   = Re
    y2[t + 512 * p] = v[p].y * sc;   // batch bp+8 = Im
  }
}

extern "C" void kernel_launch(void* const* d_in, const int* in_sizes, int n_in,
                              void* d_out, int out_size, void* d_ws, size_t ws_size,
                              hipStream_t stream) {
  const float* u    = (const float*)d_in[0];
  const float* Lre  = (const float*)d_in[1];
  const float* Lim  = (const float*)d_in[2];
  const float* Pre  = (const float*)d_in[3];
  const float* Pim  = (const float*)d_in[4];
  const float* Bre  = (const float*)d_in[5];
  const float* Bim  = (const float*)d_in[6];
  const float* Cre  = (const float*)d_in[7];
  const float* Cim  = (const float*)d_in[8];
  const float* lstep = (const float*)d_in[9];
  float* y = (float*)d_out;

  s4_prep<<<(NH * NSTATE + 255) / 256, 256, 0, stream>>>(Lre, Lim, Pre, Pim, Bre, Bim, Cre, Cim);
  s4_kernel_freq<<<NH, 1024, 0, stream>>>(lstep);
  s4_fftconv<<<NH * (NB / 2), 512, 0, stream>>>(u, y);
}

// Round 3
// 184.588 us; speedup vs baseline: 1.3022x; 1.0421x over previous
//
#include <hip/hip_runtime.h>
#include <math.h>

#define NSTATE 64
#define LEN    4096
#define NH     256
#define NB     16

// Ksym in natural order (freq output), and base-8 digit-reversed (fftconv input)
__device__ float2 g_knat[NH * LEN];
__device__ float2 g_ksym[NH * LEN];
// per-(h,n) Cauchy params: A={lam_r,lam_i,|P|^2,pad} B={v0r,v0i,v1r,v1i} C={v2r,v2i}
__device__ float4 g_pA[NH * NSTATE];
__device__ float4 g_pB[NH * NSTATE];
__device__ float2 g_pC[NH * NSTATE];

__device__ __forceinline__ int rev8_12(int p) {
  return ((p & 7) << 9) | (((p >> 3) & 7) << 6) | (((p >> 6) & 7) << 3) | (p >> 9);
}

// ---------------- complex helpers ----------------
__device__ __forceinline__ float2 cadd(float2 a, float2 b){ return make_float2(a.x+b.x, a.y+b.y); }
__device__ __forceinline__ float2 csub(float2 a, float2 b){ return make_float2(a.x-b.x, a.y-b.y); }
__device__ __forceinline__ float2 cmul(float2 a, float2 b){ return make_float2(a.x*b.x - a.y*b.y, a.x*b.y + a.y*b.x); }
__device__ __forceinline__ float2 mulnegi(float2 a){ return make_float2(a.y, -a.x); }
__device__ __forceinline__ float2 mulposi(float2 a){ return make_float2(-a.y, a.x); }

#define RSQ2 0.70710678118654752f

__device__ __forceinline__ void bfly8_fwd(float2 v[8]) {
  float2 a0 = cadd(v[0], v[4]), b0 = csub(v[0], v[4]);
  float2 a1 = cadd(v[1], v[5]), d1 = csub(v[1], v[5]);
  float2 a2 = cadd(v[2], v[6]), d2 = csub(v[2], v[6]);
  float2 a3 = cadd(v[3], v[7]), d3 = csub(v[3], v[7]);
  float2 b1 = make_float2(RSQ2 * (d1.x + d1.y), RSQ2 * (d1.y - d1.x));
  float2 b2 = mulnegi(d2);
  float2 b3 = make_float2(RSQ2 * (d3.y - d3.x), -RSQ2 * (d3.x + d3.y));
  float2 u0 = cadd(a0, a2), u1 = csub(a0, a2), u2 = cadd(a1, a3), u3 = csub(a1, a3);
  v[0] = cadd(u0, u2);
  v[2] = cadd(u1, mulnegi(u3));
  v[4] = csub(u0, u2);
  v[6] = cadd(u1, mulposi(u3));
  float2 w0 = cadd(b0, b2), w1 = csub(b0, b2), w2 = cadd(b1, b3), w3 = csub(b1, b3);
  v[1] = cadd(w0, w2);
  v[3] = cadd(w1, mulnegi(w3));
  v[5] = csub(w0, w2);
  v[7] = cadd(w1, mulposi(w3));
}

__device__ __forceinline__ void bfly8_inv(float2 v[8]) {
  float2 a0 = cadd(v[0], v[4]), b0 = csub(v[0], v[4]);
  float2 a1 = cadd(v[1], v[5]), d1 = csub(v[1], v[5]);
  float2 a2 = cadd(v[2], v[6]), d2 = csub(v[2], v[6]);
  float2 a3 = cadd(v[3], v[7]), d3 = csub(v[3], v[7]);
  float2 b1 = make_float2(RSQ2 * (d1.x - d1.y), RSQ2 * (d1.x + d1.y));
  float2 b2 = mulposi(d2);
  float2 b3 = make_float2(-RSQ2 * (d3.x + d3.y), RSQ2 * (d3.x - d3.y));
  float2 u0 = cadd(a0, a2), u1 = csub(a0, a2), u2 = cadd(a1, a3), u3 = csub(a1, a3);
  v[0] = cadd(u0, u2);
  v[2] = cadd(u1, mulposi(u3));
  v[4] = csub(u0, u2);
  v[6] = cadd(u1, mulnegi(u3));
  float2 w0 = cadd(b0, b2), w1 = csub(b0, b2), w2 = cadd(b1, b3), w3 = csub(b1, b3);
  v[1] = cadd(w0, w2);
  v[3] = cadd(w1, mulposi(w3));
  v[5] = csub(w0, w2);
  v[7] = cadd(w1, mulnegi(w3));
}

__device__ __forceinline__ void twiddle7(float2 v[8], float wr, float wi) {
  float2 w1 = make_float2(wr, wi);
  float2 w2 = cmul(w1, w1);
  float2 w3 = cmul(w2, w1);
  float2 w4 = cmul(w2, w2);
  float2 w5 = cmul(w3, w2);
  float2 w6 = cmul(w3, w3);
  float2 w7 = cmul(w4, w3);
  v[1] = cmul(v[1], w1); v[2] = cmul(v[2], w2); v[3] = cmul(v[3], w3);
  v[4] = cmul(v[4], w4); v[5] = cmul(v[5], w5); v[6] = cmul(v[6], w6);
  v[7] = cmul(v[7], w7);
}

// ---------------- param precompute ----------------
__global__ __launch_bounds__(256) void s4_prep(
    const float* __restrict__ Lre, const float* __restrict__ Lim,
    const float* __restrict__ Pre, const float* __restrict__ Pim,
    const float* __restrict__ Bre, const float* __restrict__ Bim,
    const float* __restrict__ Cre, const float* __restrict__ Cim)
{
  int idx = blockIdx.x * 256 + threadIdx.x;
  if (idx >= NH * NSTATE) return;
  float lr = Lre[idx], li = Lim[idx];
  float pr = Pre[idx], pi = Pim[idx];
  float br = Bre[idx], bi = Bim[idx];
  float cr = Cre[idx], ci = Cim[idx];
  g_pA[idx] = make_float4(lr, li, pr * pr + pi * pi, 0.0f);
  g_pB[idx] = make_float4(cr * br + ci * bi, cr * bi - ci * br,
                          cr * pr + ci * pi, cr * pi - ci * pr);
  g_pC[idx] = make_float2(pr * br + pi * bi, pr * bi - pi * br);
}

// ---------------- frequency-domain S4 kernel ----------------
// Grid NH*4 blocks x 256 threads. Thread (h, q) evaluates K at 4 points:
//   A: l=q            B: mirror (4096-q)&4095   (q==0 -> l=2048, self-paired)
//   C: l=1024+q       D: mirror 3072-q
// Symmetrization done in registers via the mirror pairs; writes natural order.
__global__ __launch_bounds__(256) void s4_kernel_freq(const float* __restrict__ log_step)
{
  const int b = blockIdx.x;
  const int h = b >> 2;
  const int q = ((b & 3) << 8) | threadIdx.x;  // 0..1023
  const float step = expf(log_step[h]);
  const float ts = 2.0f / step;
  const float NEG2PI = -6.2831853071795864769f;

  float gar, gai, car, cai, gbr, gbi, cbr, cbi;
  float gcr, gci, ccr, cci, gdr, gdi, cdr, cdi;
  {
    float so, co;
    sincosf(NEG2PI * ((float)q * (1.0f / (float)LEN)), &so, &co);
    float dr = 1.0f + co, di = so;
    float inv = 1.0f / fmaf(dr, dr, di * di);
    car = 2.0f * dr * inv; cai = -2.0f * di * inv;
    float nr = 1.0f - co, ni = -so;
    gar = ts * (fmaf(nr, dr, ni * di) * inv);
    gai = ts * (fmaf(ni, dr, -nr * di) * inv);
  }
  if (q == 0) {           // point B is l = 2048 (self-paired), compute directly
    float so, co;
    sincosf(NEG2PI * 0.5f, &so, &co);
    float dr = 1.0f + co, di = so;
    float inv = 1.0f / fmaf(dr, dr, di * di);
    cbr = 2.0f * dr * inv; cbi = -2.0f * di * inv;
    float nr = 1.0f - co, ni = -so;
    gbr = ts * (fmaf(nr, dr, ni * di) * inv);
    gbi = ts * (fmaf(ni, dr, -nr * di) * inv);
  } else {                // B = mirror of A: Omega -> conj => g,c -> conj
    gbr = gar; gbi = -gai; cbr = car; cbi = -cai;
  }
  {
    float so, co;
    sincosf(NEG2PI * ((float)(q + 1024) * (1.0f / (float)LEN)), &so, &co);
    float dr = 1.0f + co, di = so;
    float inv = 1.0f / fmaf(dr, dr, di * di);
    ccr = 2.0f * dr * inv; cci = -2.0f * di * inv;
    float nr = 1.0f - co, ni = -so;
    gcr = ts * (fmaf(nr, dr, ni * di) * inv);
    gci = ts * (fmaf(ni, dr, -nr * di) * inv);
  }
  gdr = gcr; gdi = -gci; cdr = ccr; cdi = -cci;

  float A00r=0,A00i=0,A01r=0,A01i=0,A10r=0,A10i=0,A11r=0,A11i=0;
  float B00r=0,B00i=0,B01r=0,B01i=0,B10r=0,B10i=0,B11r=0,B11i=0;
  float C00r=0,C00i=0,C01r=0,C01i=0,C10r=0,C10i=0,C11r=0,C11i=0;
  float D00r=0,D00i=0,D01r=0,D01i=0,D10r=0,D10i=0,D11r=0,D11i=0;

  const float4* __restrict__ pa = g_pA + h * NSTATE;
  const float4* __restrict__ pb = g_pB + h * NSTATE;
  const float2* __restrict__ pc = g_pC + h * NSTATE;

#define CAUCHY(gre, gim, k00r,k00i,k01r,k01i,k10r,k10i,k11r,k11i)            \
  {                                                                          \
    float rd = gre - Av.x, id = gim - Av.y;                                  \
    float idn = __builtin_amdgcn_rcpf(fmaf(rd, rd, id * id));                \
    float ir = rd * idn, ii = -(id * idn);                                   \
    k00r = fmaf(Bv.x, ir, k00r); k00r = fmaf(-Bv.y, ii, k00r);               \
    k00i = fmaf(Bv.x, ii, k00i); k00i = fmaf(Bv.y, ir, k00i);                \
    k01r = fmaf(Bv.z, ir, k01r); k01r = fmaf(-Bv.w, ii, k01r);               \
    k01i = fmaf(Bv.z, ii, k01i); k01i = fmaf(Bv.w, ir, k01i);                \
    k10r = fmaf(Cv.x, ir, k10r); k10r = fmaf(-Cv.y, ii, k10r);               \
    k10i = fmaf(Cv.x, ii, k10i); k10i = fmaf(Cv.y, ir, k10i);                \
    k11r = fmaf(Av.z, ir, k11r); k11i = fmaf(Av.z, ii, k11i);                \
  }

#pragma unroll 4
  for (int n = 0; n < NSTATE; ++n) {
    float4 Av = pa[n];
    float4 Bv = pb[n];
    float2 Cv = pc[n];
    CAUCHY(gar, gai, A00r,A00i,A01r,A01i,A10r,A10i,A11r,A11i)
    CAUCHY(gbr, gbi, B00r,B00i,B01r,B01i,B10r,B10i,B11r,B11i)
    CAUCHY(gcr, gci, C00r,C00i,C01r,C01i,C10r,C10i,C11r,C11i)
    CAUCHY(gdr, gdi, D00r,D00i,D01r,D01i,D10r,D10i,D11r,D11i)
  }
#undef CAUCHY

#define FINISH(cr_, ci_, k00r,k00i,k01r,k01i,k10r,k10i,k11r,k11i, Kr, Ki)    \
  {                                                                          \
    float rr = 1.0f + k11r, ri = k11i;                                       \
    float rinv = 1.0f / fmaf(rr, rr, ri * ri);                               \
    float pr_ = k01r * k10r - k01i * k10i;                                   \
    float pi_ = k01r * k10i + k01i * k10r;                                   \
    float wr = (pr_ * rr + pi_ * ri) * rinv;                                 \
    float wi = (pi_ * rr - pr_ * ri) * rinv;                                 \
    float sr = k00r - wr, si = k00i - wi;                                    \
    Kr = cr_ * sr - ci_ * si; Ki = cr_ * si + ci_ * sr;                      \
  }

  float Kar, Kai, Kbr, Kbi, Kcr, Kci, Kdr, Kdi;
  FINISH(car, cai, A00r,A00i,A01r,A01i,A10r,A10i,A11r,A11i, Kar, Kai)
  FINISH(cbr, cbi, B00r,B00i,B01r,B01i,B10r,B10i,B11r,B11i, Kbr, Kbi)
  FINISH(ccr, cci, C00r,C00i,C01r,C01i,C10r,C10i,C11r,C11i, Kcr, Kci)
  FINISH(cdr, cdi, D00r,D00i,D01r,D01i,D10r,D10i,D11r,D11i, Kdr, Kdi)
#undef FINISH

  float2* out = g_knat + (size_t)h * LEN;
  if (q == 0) {
    out[0]    = make_float2(Kar, 0.0f);     // Ksym[0]    = Re K[0]
    out[2048] = make_float2(Kbr, 0.0f);     // Ksym[2048] = Re K[2048]
  } else {
    float fr = 0.5f * (Kar + Kbr), fi = 0.5f * (Kai - Kbi);
    out[q]        = make_float2(fr, fi);
    out[LEN - q]  = make_float2(fr, -fi);   // conj pair
  }
  {
    float fr = 0.5f * (Kcr + Kdr), fi = 0.5f * (Kci - Kdi);
    out[1024 + q] = make_float2(fr, fi);
    out[3072 - q] = make_float2(fr, -fi);
  }
}

// ---------------- reorder natural -> base-8 digit-reversed ----------------
__global__ __launch_bounds__(256) void s4_reorder()
{
  __shared__ float2 s[LEN];   // XOR-swizzled: phys(i) = i ^ ((i>>6)&63)
  const int h = blockIdx.x, t = threadIdx.x;
  const float2* __restrict__ in = g_knat + (size_t)h * LEN;
  float2* __restrict__ out = g_ksym + (size_t)h * LEN;
  for (int i = t; i < LEN; i += 256) s[i ^ ((i >> 6) & 63)] = in[i];
  __syncthreads();
  for (int p = t; p < LEN; p += 256) {
    int l = rev8_12(p);
    out[p] = s[l ^ ((l >> 6) & 63)];
  }
}

// ---------------- FFT convolution: register radix-8, 4096 = 8^4 ----------------
__global__ __launch_bounds__(512) void s4_fftconv(const float* __restrict__ u,
                                                 float* __restrict__ y)
{
  __shared__ float2 X[4608];

  const int t = threadIdx.x;
  const int bid = blockIdx.x;
  const int h  = bid & (NH - 1);
  const int bp = bid >> 8;

  float c1, s1, c2, s2, c3, s3;
  sincosf((float)t         * (-6.2831853071795864769f / 4096.0f), &s1, &c1);
  sincosf((float)(t & 63)  * (-6.2831853071795864769f /  512.0f), &s2, &c2);
  sincosf((float)(t & 7)   * (-6.2831853071795864769f /   64.0f), &s3, &c3);

  const float* u1 = u + ((size_t)bp * NH + h) * LEN;
  const float* u2 = u + ((size_t)(bp + 8) * NH + h) * LEN;

  float2 v[8];
#pragma unroll
  for (int m = 0; m < 8; ++m)
    v[m] = make_float2(u1[t + 512 * m], u2[t + 512 * m]);
  bfly8_fwd(v);
  twiddle7(v, c1, s1);
#pragma unroll
  for (int m = 0; m < 8; ++m) X[t + 512 * m] = v[m];
  __syncthreads();

  {
    int B = t >> 6, j = t & 63, base = B * 512 + j;
#pragma unroll
    for (int m = 0; m < 8; ++m) v[m] = X[base + 64 * m];
  }
  __syncthreads();
  bfly8_fwd(v);
  twiddle7(v, c2, s2);
  {
    int B = t >> 6, j = t & 63;
#pragma unroll
    for (int m = 0; m < 8; ++m) X[68 * (8 * B + m) + j] = v[m];
  }
  __syncthreads();

  {
    int b = t >> 3, j = t & 7;
#pragma unroll
    for (int m = 0; m < 8; ++m) v[m] = X[68 * b + j + 8 * m];
  }
  __syncthreads();
  bfly8_fwd(v);
  twiddle7(v, c3, s3);
  {
    int b = t >> 3, j = t & 7;
#pragma unroll
    for (int m = 0; m < 8; ++m) X[9 * (8 * b + m) + j] = v[m];
  }
  __syncthreads();

  {
    const float4* kp = (const float4*)(g_ksym + (size_t)h * LEN + 8 * t);
    float4 k0 = kp[0], k1 = kp[1], k2 = kp[2], k3 = kp[3];
#pragma unroll
    for (int m = 0; m < 8; ++m) v[m] = X[9 * t + m];
    bfly8_fwd(v);
    v[0] = cmul(v[0], make_float2(k0.x, k0.y));
    v[1] = cmul(v[1], make_float2(k0.z, k0.w));
    v[2] = cmul(v[2], make_float2(k1.x, k1.y));
    v[3] = cmul(v[3], make_float2(k1.z, k1.w));
    v[4] = cmul(v[4], make_float2(k2.x, k2.y));
    v[5] = cmul(v[5], make_float2(k2.z, k2.w));
    v[6] = cmul(v[6], make_float2(k3.x, k3.y));
    v[7] = cmul(v[7], make_float2(k3.z, k3.w));
    bfly8_inv(v);
#pragma unroll
    for (int p = 0; p < 8; ++p) X[9 * t + p] = v[p];
  }
  __syncthreads();

  {
    int b = t >> 3, j = t & 7;
#pragma unroll
    for (int m = 0; m < 8; ++m) v[m] = X[9 * (8 * b + m) + j];
  }
  twiddle7(v, c3, -s3);
  bfly8_inv(v);
  __syncthreads();
  {
    int b = t >> 3, j = t & 7;
#pragma unroll
    for (int p = 0; p < 8; ++p) X[68 * b + j + 8 * p] = v[p];
  }
  __syncthreads();

  {
    int B = t >> 6, j = t & 63;
#pragma unroll
    for (int m = 0; m < 8; ++m) v[m] = X[68 * (8 * B + m) + j];
  }
  twiddle7(v, c2, -s2);
  bfly8_inv(v);
  __syncthreads();
  {
    int B = t >> 6, j = t & 63, base = B * 512 + j;
#pragma unroll
    for (int p = 0; p < 8; ++p) X[base + 64 * p] = v[p];
  }
  __syncthreads();

#pragma unroll
  for (int m = 0; m < 8; ++m) v[m] = X[t + 512 * m];
  twiddle7(v, c1, -s1);
  bfly8_inv(v);

  float* y1 = y + ((size_t)bp * NH + h) * LEN;
  float* y2 = y + ((size_t)(bp + 8) * NH + h) * LEN;
  const float sc = 1.0f / (float)LEN;
#pragma unroll
  for (int p = 0; p < 8; ++p) {
    y1[t + 512 * p] = v[p].x * sc;
    y2[t + 512 * p] = v[p].y * sc;
  }
}

extern "C" void kernel_launch(void* const* d_in, const int* in_sizes, int n_in,
                              void* d_out, int out_size, void* d_ws, size_t ws_size,
                              hipStream_t stream) {
  const float* u    = (const float*)d_in[0];
  const float* Lre  = (const float*)d_in[1];
  const float* Lim  = (const float*)d_in[2];
  const float* Pre  = (const float*)d_in[3];
  const float* Pim  = (const float*)d_in[4];
  const float* Bre  = (const float*)d_in[5];
  const float* Bim  = (const float*)d_in[6];
  const float* Cre  = (const float*)d_in[7];
  const float* Cim  = (const float*)d_in[8];
  const float* lstep = (const float*)d_in[9];
  float* y = (float*)d_out;

  s4_prep<<<(NH * NSTATE + 255) / 256, 256, 0, stream>>>(Lre, Lim, Pre, Pim, Bre, Bim, Cre, Cim);
  s4_kernel_freq<<<NH * 4, 256, 0, stream>>>(lstep);
  s4_reorder<<<NH, 256, 0, stream>>>();
  s4_fftconv<<<NH * (NB / 2), 512, 0, stream>>>(u, y);
}